// Round 10
// baseline (58.228 us; speedup 1.0000x reference)
//
#include <hip/hip_runtime.h>
#include <cmath>

#define H 1024
#define V 50257
#define L 512
#define NBGEMV 1024   // grid-stride GEMV blocks (exactly 4/CU)
#define NPART 256     // attn numerator partials (2 rows each)

typedef float f4 __attribute__((ext_vector_type(4)));

__device__ __forceinline__ float wred_sum(float v) {
#pragma unroll
    for (int o = 32; o > 0; o >>= 1) v += __shfl_xor(v, o, 64);
    return v;
}
__device__ __forceinline__ float dot4f(f4 a, f4 b) {
    return a.x * b.x + a.y * b.y + a.z * b.z + a.w * b.w;
}
__device__ __forceinline__ void ms_merge(float& m, float& s, float m2, float s2) {
    float M = fmaxf(m, m2);
    if (M == -INFINITY) { m = M; s = 0.f; return; }
    s = s * expf(m - M) + s2 * expf(m2 - M);
    m = M;
}

// K1 (1024 blocks, exactly 4/CU, ~uniform 16-24KB per block):
//  blocks [0,256):  2 attn rows; wave wv handles (row = 2b+(wv>>1), k-half = wv&1);
//                   exp-logits -> elg, then 2-row weighted-enc partial -> pbuf[b].
//  blocks [256,1024): gh[j] = h . W_hh[j,:] + b_hh[j], wave-per-row.
__global__ void k_phase1(const int* __restrict__ tok,
                         const float* __restrict__ hid,
                         const float* __restrict__ emb,
                         const float* __restrict__ Wa,
                         const float* __restrict__ ba,
                         const float* __restrict__ enc,
                         const float* __restrict__ Whh,
                         const float* __restrict__ bhh,
                         float* __restrict__ elg,
                         float* __restrict__ pbuf,   // [256][1024]
                         float* __restrict__ gh) {
    const int t = threadIdx.x, lane = t & 63, wv = t >> 6, b = blockIdx.x;
    const f4* h4 = (const f4*)hid;
    if (b < NPART) {
        const int row = 2 * b + (wv >> 1);
        const int half = wv & 1;
        const f4* e4 = (const f4*)(emb + (size_t)tok[0] * H);
        const f4* wr = (const f4*)(Wa + (size_t)row * 2048);
        float acc = 0.f;
#pragma unroll
        for (int k = 0; k < 4; ++k) {
            int f = half * 256 + 64 * k + lane;    // [0, 512)
            f4 s = (f < 256) ? e4[f] : h4[f - 256];
            acc += dot4f(wr[f], s);
        }
        acc = wred_sum(acc);
        __shared__ float sp[4];
        __shared__ float se[2];
        if (lane == 0) sp[wv] = acc;
        __syncthreads();
        if (t == 0) {
            float E0 = expf(sp[0] + sp[1] + ba[2 * b]);
            float E1 = expf(sp[2] + sp[3] + ba[2 * b + 1]);
            se[0] = E0; se[1] = E1;
            elg[2 * b] = E0; elg[2 * b + 1] = E1;
        }
        __syncthreads();
        f4 a = se[0] * ((const f4*)(enc + (size_t)(2 * b) * H))[t]
             + se[1] * ((const f4*)(enc + (size_t)(2 * b + 1) * H))[t];
        ((f4*)pbuf)[b * 256 + t] = a;
    } else {
        const int j = (b - NPART) * 4 + wv;   // [0, 3072)
        const f4* wh = (const f4*)(Whh + (size_t)j * H);
        float acc = 0.f;
#pragma unroll
        for (int k = 0; k < 4; ++k) {
            int f = 64 * k + lane;
            acc += dot4f(wh[f], h4[f]);
        }
        acc = wred_sum(acc);
        if (lane == 0) gh[j] = acc + bhh[j];
    }
}

// K2 (16 blocks): deterministic reduce of 256 partials -> aa (invS-scaled).
//  Block b owns f4-columns [16b, 16b+16); thread (g=t>>4, c=t&15) sums 16 stripes.
//  Block 0 also writes attn_weights.
__global__ void k_reduce(const float* __restrict__ elg,
                         const float* __restrict__ pbuf,
                         float* __restrict__ aa,
                         float* __restrict__ wout) {
    const int t = threadIdx.x, b = blockIdx.x;
    const int g = t >> 4, c = t & 15;
    __shared__ float red[4];
    const float e0 = elg[t], e1 = elg[t + 256];
    float s = wred_sum(e0 + e1);
    if ((t & 63) == 0) red[t >> 6] = s;
    __syncthreads();
    const float invS = 1.f / (red[0] + red[1] + red[2] + red[3]);
    const int col = b * 16 + c;
    f4 a = {0.f, 0.f, 0.f, 0.f};
#pragma unroll
    for (int i = 0; i < 16; ++i)
        a += ((const f4*)pbuf)[(size_t)(g + 16 * i) * 256 + col];
    __shared__ f4 racc[16][16];
    racc[g][c] = a;
    __syncthreads();
    if (g == 0) {
        f4 tot = {0.f, 0.f, 0.f, 0.f};
#pragma unroll
        for (int i = 0; i < 16; ++i) tot += racc[i][c];
        ((f4*)aa)[col] = tot * invS;
    }
    if (b == 0) { wout[t] = e0 * invS; wout[t + 256] = e1 * invS; }
}

// K3 (256 blocks): x[j] = relu([emb, aa] . Wc[j,:] + bc[j]); wave-per-row.
__global__ void k_comb(const int* __restrict__ tok,
                       const float* __restrict__ emb,
                       const float* __restrict__ aa,
                       const float* __restrict__ Wc,
                       const float* __restrict__ bcb,
                       float* __restrict__ xv) {
    const int lane = threadIdx.x & 63, wv = threadIdx.x >> 6;
    const int j = blockIdx.x * 4 + wv;
    const f4* e4 = (const f4*)(emb + (size_t)tok[0] * H);
    const f4* a4 = (const f4*)aa;
    const f4* wr = (const f4*)(Wc + (size_t)j * 2048);
    float acc = 0.f;
#pragma unroll
    for (int k = 0; k < 4; ++k) {
        int f = 64 * k + lane;
        acc += dot4f(wr[f], e4[f]);
        acc += dot4f(wr[256 + f], a4[f]);
    }
    acc = wred_sum(acc);
    if (lane == 0) xv[j] = fmaxf(acc + bcb[j], 0.f);
}

// K4 (256 blocks): fused gates+GRU; wave per j.
__global__ void k_gates_gru(const float* __restrict__ xv,
                            const float* __restrict__ hid,
                            const float* __restrict__ Wih,
                            const float* __restrict__ bih,
                            const float* __restrict__ gh,
                            float* __restrict__ hn_out,
                            float* __restrict__ hn_ws) {
    const int lane = threadIdx.x & 63, wv = threadIdx.x >> 6;
    const int j = blockIdx.x * 4 + wv;
    const f4* x4 = (const f4*)xv;
    f4 xreg[4];
#pragma unroll
    for (int k = 0; k < 4; ++k) xreg[k] = x4[64 * k + lane];
    float g[3];
#pragma unroll
    for (int p = 0; p < 3; ++p) {
        const f4* wr = (const f4*)(Wih + (size_t)(j + p * H) * H);
        float acc = 0.f;
#pragma unroll
        for (int k = 0; k < 4; ++k) acc += dot4f(wr[64 * k + lane], xreg[k]);
        g[p] = wred_sum(acc) + bih[j + p * H];
    }
    if (lane == 0) {
        float r = 1.f / (1.f + expf(-(g[0] + gh[j])));
        float z = 1.f / (1.f + expf(-(g[1] + gh[j + H])));
        float n = tanhf(g[2] + r * gh[j + 2 * H]);
        float hv = (1.f - z) * n + z * hid[j];
        hn_out[j] = hv;
        hn_ws[j] = hv;
    }
}

// K5 (1024 blocks, exactly 4/CU): grid-stride GEMV, 2-row unrolled.
//  SINGLE CHANGE THIS ROUND: Wo is streamed with nontemporal loads (no L2
//  read-allocate for the 206 MB one-shot stream). Everything else identical.
__global__ void k_out_gemv(const float* __restrict__ hn,
                           const float* __restrict__ Wo,
                           const float* __restrict__ bo,
                           float* __restrict__ logits,
                           float* __restrict__ pm,
                           float* __restrict__ ps) {
    const int lane = threadIdx.x & 63, wv = threadIdx.x >> 6;
    const int b = blockIdx.x;
    const int gw = b * 4 + wv;            // [0, 4096)
    const f4* h4 = (const f4*)hn;
    f4 hreg[4];
#pragma unroll
    for (int k = 0; k < 4; ++k) hreg[k] = h4[64 * k + lane];
    float m = -INFINITY, s = 0.f;
    int v = gw;
    for (; v < V - 4096; v += 8192) {
        const f4* wr0 = (const f4*)(Wo + (size_t)v * H);
        const f4* wr1 = (const f4*)(Wo + (size_t)(v + 4096) * H);
        f4 a0[4], a1[4];
#pragma unroll
        for (int k = 0; k < 4; ++k) a0[k] = __builtin_nontemporal_load(wr0 + 64 * k + lane);
#pragma unroll
        for (int k = 0; k < 4; ++k) a1[k] = __builtin_nontemporal_load(wr1 + 64 * k + lane);
        float acc0 = 0.f, acc1 = 0.f;
#pragma unroll
        for (int k = 0; k < 4; ++k) { acc0 += dot4f(a0[k], hreg[k]); acc1 += dot4f(a1[k], hreg[k]); }
#pragma unroll
        for (int o = 32; o > 0; o >>= 1) {
            acc0 += __shfl_xor(acc0, o, 64);
            acc1 += __shfl_xor(acc1, o, 64);
        }
        acc0 += bo[v];
        acc1 += bo[v + 4096];
        if (lane == 0) { logits[v] = acc0; logits[v + 4096] = acc1; }
        float M = fmaxf(m, fmaxf(acc0, acc1));
        s = s * expf(m - M) + expf(acc0 - M) + expf(acc1 - M);
        m = M;
    }
    if (v < V) {
        const f4* wr = (const f4*)(Wo + (size_t)v * H);
        float acc = 0.f;
#pragma unroll
        for (int k = 0; k < 4; ++k)
            acc += dot4f(__builtin_nontemporal_load(wr + 64 * k + lane), hreg[k]);
        acc = wred_sum(acc) + bo[v];
        if (lane == 0) logits[v] = acc;
        float M = fmaxf(m, acc);
        s = s * expf(m - M) + expf(acc - M);
        m = M;
    }
    __shared__ float smm[4], sms[4];
    if (lane == 0) { smm[wv] = m; sms[wv] = s; }
    __syncthreads();
    if (threadIdx.x == 0) {
        float M = smm[0], S = sms[0];
#pragma unroll
        for (int i = 1; i < 4; ++i) ms_merge(M, S, smm[i], sms[i]);
        pm[b] = M; ps[b] = S;
    }
}

// K6 (197 blocks): redundant (m,s) reduce over 1024 partials -> C; subtract.
__global__ void k_finalize(float* __restrict__ out,
                           const float* __restrict__ pm,
                           const float* __restrict__ ps) {
    const int t = threadIdx.x, lane = t & 63, wv = t >> 6;
    float m = -INFINITY, s = 0.f;
    for (int i = t; i < NBGEMV; i += 256) ms_merge(m, s, pm[i], ps[i]);
#pragma unroll
    for (int o = 32; o > 0; o >>= 1) {
        float m2 = __shfl_xor(m, o, 64);
        float s2 = __shfl_xor(s, o, 64);
        ms_merge(m, s, m2, s2);
    }
    __shared__ float smm[4], sms[4];
    __shared__ float Cs;
    if (lane == 0) { smm[wv] = m; sms[wv] = s; }
    __syncthreads();
    if (t == 0) {
        float M = smm[0], S = sms[0];
#pragma unroll
        for (int i = 1; i < 4; ++i) ms_merge(M, S, smm[i], sms[i]);
        Cs = M + logf(S);
    }
    __syncthreads();
    const float C = Cs;
    const int v = blockIdx.x * 256 + t;
    if (v < V) out[v] -= C;
}

extern "C" void kernel_launch(void* const* d_in, const int* in_sizes, int n_in,
                              void* d_out, int out_size, void* d_ws, size_t ws_size,
                              hipStream_t stream) {
    const int*   tok = (const int*)d_in[0];
    const float* hid = (const float*)d_in[1];
    const float* enc = (const float*)d_in[2];
    const float* emb = (const float*)d_in[3];
    const float* Wa  = (const float*)d_in[4];
    const float* ba  = (const float*)d_in[5];
    const float* Wc  = (const float*)d_in[6];
    const float* bc  = (const float*)d_in[7];
    const float* Wih = (const float*)d_in[8];
    const float* Whh = (const float*)d_in[9];
    const float* bih = (const float*)d_in[10];
    const float* bhh = (const float*)d_in[11];
    const float* Wo  = (const float*)d_in[12];
    const float* bo  = (const float*)d_in[13];

    float* out = (float*)d_out;   // [V | H | L]
    float* ws  = (float*)d_ws;
    float* elg  = ws;                 // 512
    float* gh   = ws + 512;           // 3072
    float* aa   = ws + 3584;          // 1024 (16B aligned)
    float* xv   = ws + 4608;          // 1024 (16B aligned)
    float* hn   = ws + 5632;          // 1024 (16B aligned)
    float* pm   = ws + 6656;          // 1024
    float* psum = ws + 7680;          // 1024
    float* pbuf = ws + 8704;          // 256*1024 (16B aligned)

    float* out_logits = out;          // V
    float* out_hnew   = out + V;      // H
    float* out_attnw  = out + V + H;  // L

    k_phase1<<<NPART + 768, 256, 0, stream>>>(tok, hid, emb, Wa, ba, enc, Whh, bhh,
                                              elg, pbuf, gh);
    k_reduce<<<16, 256, 0, stream>>>(elg, pbuf, aa, out_attnw);
    k_comb<<<256, 256, 0, stream>>>(tok, emb, aa, Wc, bc, xv);
    k_gates_gru<<<256, 256, 0, stream>>>(xv, hid, Wih, bih, gh, out_hnew, hn);
    k_out_gemv<<<NBGEMV, 256, 0, stream>>>(hn, Wo, bo, out_logits, pm, psum);
    k_finalize<<<197, 256, 0, stream>>>(out_logits, pm, psum);
}

// Round 11
// 56.802 us; speedup vs baseline: 1.0251x; 1.0251x over previous
//
#include <hip/hip_runtime.h>
#include <cmath>

#define H 1024
#define V 50257
#define L 512
#define NBGEMV 2048   // grid-stride GEMV blocks (exactly 8/CU, 8 waves/SIMD)
#define GSTR (NBGEMV * 4)
#define NPART 256     // attn numerator partials (2 rows each)

typedef float f4 __attribute__((ext_vector_type(4)));

__device__ __forceinline__ float wred_sum(float v) {
#pragma unroll
    for (int o = 32; o > 0; o >>= 1) v += __shfl_xor(v, o, 64);
    return v;
}
__device__ __forceinline__ float dot4f(f4 a, f4 b) {
    return a.x * b.x + a.y * b.y + a.z * b.z + a.w * b.w;
}
__device__ __forceinline__ void ms_merge(float& m, float& s, float m2, float s2) {
    float M = fmaxf(m, m2);
    if (M == -INFINITY) { m = M; s = 0.f; return; }
    s = s * expf(m - M) + s2 * expf(m2 - M);
    m = M;
}

// K1 (1024 blocks, exactly 4/CU, ~uniform 16-24KB per block):
//  blocks [0,256):  2 attn rows; wave wv handles (row = 2b+(wv>>1), k-half = wv&1);
//                   exp-logits -> elg, then 2-row weighted-enc partial -> pbuf[b].
//  blocks [256,1024): gh[j] = h . W_hh[j,:] + b_hh[j], wave-per-row.
__global__ void k_phase1(const int* __restrict__ tok,
                         const float* __restrict__ hid,
                         const float* __restrict__ emb,
                         const float* __restrict__ Wa,
                         const float* __restrict__ ba,
                         const float* __restrict__ enc,
                         const float* __restrict__ Whh,
                         const float* __restrict__ bhh,
                         float* __restrict__ elg,
                         float* __restrict__ pbuf,   // [256][1024]
                         float* __restrict__ gh) {
    const int t = threadIdx.x, lane = t & 63, wv = t >> 6, b = blockIdx.x;
    const f4* h4 = (const f4*)hid;
    if (b < NPART) {
        const int row = 2 * b + (wv >> 1);
        const int half = wv & 1;
        const f4* e4 = (const f4*)(emb + (size_t)tok[0] * H);
        const f4* wr = (const f4*)(Wa + (size_t)row * 2048);
        float acc = 0.f;
#pragma unroll
        for (int k = 0; k < 4; ++k) {
            int f = half * 256 + 64 * k + lane;    // [0, 512)
            f4 s = (f < 256) ? e4[f] : h4[f - 256];
            acc += dot4f(wr[f], s);
        }
        acc = wred_sum(acc);
        __shared__ float sp[4];
        __shared__ float se[2];
        if (lane == 0) sp[wv] = acc;
        __syncthreads();
        if (t == 0) {
            float E0 = expf(sp[0] + sp[1] + ba[2 * b]);
            float E1 = expf(sp[2] + sp[3] + ba[2 * b + 1]);
            se[0] = E0; se[1] = E1;
            elg[2 * b] = E0; elg[2 * b + 1] = E1;
        }
        __syncthreads();
        f4 a = se[0] * ((const f4*)(enc + (size_t)(2 * b) * H))[t]
             + se[1] * ((const f4*)(enc + (size_t)(2 * b + 1) * H))[t];
        ((f4*)pbuf)[b * 256 + t] = a;
    } else {
        const int j = (b - NPART) * 4 + wv;   // [0, 3072)
        const f4* wh = (const f4*)(Whh + (size_t)j * H);
        float acc = 0.f;
#pragma unroll
        for (int k = 0; k < 4; ++k) {
            int f = 64 * k + lane;
            acc += dot4f(wh[f], h4[f]);
        }
        acc = wred_sum(acc);
        if (lane == 0) gh[j] = acc + bhh[j];
    }
}

// K2 (16 blocks): deterministic reduce of 256 partials -> aa (invS-scaled).
//  Block b owns f4-columns [16b, 16b+16); thread (g=t>>4, c=t&15) sums 16 stripes.
//  Block 0 also writes attn_weights.
__global__ void k_reduce(const float* __restrict__ elg,
                         const float* __restrict__ pbuf,
                         float* __restrict__ aa,
                         float* __restrict__ wout) {
    const int t = threadIdx.x, b = blockIdx.x;
    const int g = t >> 4, c = t & 15;
    __shared__ float red[4];
    const float e0 = elg[t], e1 = elg[t + 256];
    float s = wred_sum(e0 + e1);
    if ((t & 63) == 0) red[t >> 6] = s;
    __syncthreads();
    const float invS = 1.f / (red[0] + red[1] + red[2] + red[3]);
    const int col = b * 16 + c;
    f4 a = {0.f, 0.f, 0.f, 0.f};
#pragma unroll
    for (int i = 0; i < 16; ++i)
        a += ((const f4*)pbuf)[(size_t)(g + 16 * i) * 256 + col];
    __shared__ f4 racc[16][16];
    racc[g][c] = a;
    __syncthreads();
    if (g == 0) {
        f4 tot = {0.f, 0.f, 0.f, 0.f};
#pragma unroll
        for (int i = 0; i < 16; ++i) tot += racc[i][c];
        ((f4*)aa)[col] = tot * invS;
    }
    if (b == 0) { wout[t] = e0 * invS; wout[t + 256] = e1 * invS; }
}

// K3 (256 blocks): x[j] = relu([emb, aa] . Wc[j,:] + bc[j]); wave-per-row.
__global__ void k_comb(const int* __restrict__ tok,
                       const float* __restrict__ emb,
                       const float* __restrict__ aa,
                       const float* __restrict__ Wc,
                       const float* __restrict__ bcb,
                       float* __restrict__ xv) {
    const int lane = threadIdx.x & 63, wv = threadIdx.x >> 6;
    const int j = blockIdx.x * 4 + wv;
    const f4* e4 = (const f4*)(emb + (size_t)tok[0] * H);
    const f4* a4 = (const f4*)aa;
    const f4* wr = (const f4*)(Wc + (size_t)j * 2048);
    float acc = 0.f;
#pragma unroll
    for (int k = 0; k < 4; ++k) {
        int f = 64 * k + lane;
        acc += dot4f(wr[f], e4[f]);
        acc += dot4f(wr[256 + f], a4[f]);
    }
    acc = wred_sum(acc);
    if (lane == 0) xv[j] = fmaxf(acc + bcb[j], 0.f);
}

// K4 (256 blocks): fused gates+GRU; wave per j.
__global__ void k_gates_gru(const float* __restrict__ xv,
                            const float* __restrict__ hid,
                            const float* __restrict__ Wih,
                            const float* __restrict__ bih,
                            const float* __restrict__ gh,
                            float* __restrict__ hn_out,
                            float* __restrict__ hn_ws) {
    const int lane = threadIdx.x & 63, wv = threadIdx.x >> 6;
    const int j = blockIdx.x * 4 + wv;
    const f4* x4 = (const f4*)xv;
    f4 xreg[4];
#pragma unroll
    for (int k = 0; k < 4; ++k) xreg[k] = x4[64 * k + lane];
    float g[3];
#pragma unroll
    for (int p = 0; p < 3; ++p) {
        const f4* wr = (const f4*)(Wih + (size_t)(j + p * H) * H);
        float acc = 0.f;
#pragma unroll
        for (int k = 0; k < 4; ++k) acc += dot4f(wr[64 * k + lane], xreg[k]);
        g[p] = wred_sum(acc) + bih[j + p * H];
    }
    if (lane == 0) {
        float r = 1.f / (1.f + expf(-(g[0] + gh[j])));
        float z = 1.f / (1.f + expf(-(g[1] + gh[j + H])));
        float n = tanhf(g[2] + r * gh[j + 2 * H]);
        float hv = (1.f - z) * n + z * hid[j];
        hn_out[j] = hv;
        hn_ws[j] = hv;
    }
}

// K5 (2048 blocks, exactly 8/CU = max occupancy): grid-stride GEMV, R8's
//  simple per-row loop (nt loads reverted — R10 showed −2.3µs). SINGLE CHANGE
//  vs R8: 2x blocks for 2x TLP (8 waves/SIMD). Online (m,s) per wave.
__global__ void k_out_gemv(const float* __restrict__ hn,
                           const float* __restrict__ Wo,
                           const float* __restrict__ bo,
                           float* __restrict__ logits,
                           float* __restrict__ pm,
                           float* __restrict__ ps) {
    const int lane = threadIdx.x & 63, wv = threadIdx.x >> 6;
    const int b = blockIdx.x;
    const int gw = b * 4 + wv;            // [0, GSTR)
    const f4* h4 = (const f4*)hn;
    f4 hreg[4];
#pragma unroll
    for (int k = 0; k < 4; ++k) hreg[k] = h4[64 * k + lane];
    float m = -INFINITY, s = 0.f;
    for (int v = gw; v < V; v += GSTR) {
        const f4* wr = (const f4*)(Wo + (size_t)v * H);
        float acc = 0.f;
#pragma unroll
        for (int k = 0; k < 4; ++k) acc += dot4f(wr[64 * k + lane], hreg[k]);
        acc = wred_sum(acc) + bo[v];
        if (lane == 0) logits[v] = acc;
        float M = fmaxf(m, acc);
        s = s * expf(m - M) + expf(acc - M);
        m = M;
    }
    __shared__ float smm[4], sms[4];
    if (lane == 0) { smm[wv] = m; sms[wv] = s; }
    __syncthreads();
    if (threadIdx.x == 0) {
        float M = smm[0], S = sms[0];
#pragma unroll
        for (int i = 1; i < 4; ++i) ms_merge(M, S, smm[i], sms[i]);
        pm[b] = M; ps[b] = S;
    }
}

// K6 (197 blocks): redundant (m,s) reduce over 2048 partials -> C; subtract.
__global__ void k_finalize(float* __restrict__ out,
                           const float* __restrict__ pm,
                           const float* __restrict__ ps) {
    const int t = threadIdx.x, lane = t & 63, wv = t >> 6;
    float m = -INFINITY, s = 0.f;
    for (int i = t; i < NBGEMV; i += 256) ms_merge(m, s, pm[i], ps[i]);
#pragma unroll
    for (int o = 32; o > 0; o >>= 1) {
        float m2 = __shfl_xor(m, o, 64);
        float s2 = __shfl_xor(s, o, 64);
        ms_merge(m, s, m2, s2);
    }
    __shared__ float smm[4], sms[4];
    __shared__ float Cs;
    if (lane == 0) { smm[wv] = m; sms[wv] = s; }
    __syncthreads();
    if (t == 0) {
        float M = smm[0], S = sms[0];
#pragma unroll
        for (int i = 1; i < 4; ++i) ms_merge(M, S, smm[i], sms[i]);
        Cs = M + logf(S);
    }
    __syncthreads();
    const float C = Cs;
    const int v = blockIdx.x * 256 + t;
    if (v < V) out[v] -= C;
}

extern "C" void kernel_launch(void* const* d_in, const int* in_sizes, int n_in,
                              void* d_out, int out_size, void* d_ws, size_t ws_size,
                              hipStream_t stream) {
    const int*   tok = (const int*)d_in[0];
    const float* hid = (const float*)d_in[1];
    const float* enc = (const float*)d_in[2];
    const float* emb = (const float*)d_in[3];
    const float* Wa  = (const float*)d_in[4];
    const float* ba  = (const float*)d_in[5];
    const float* Wc  = (const float*)d_in[6];
    const float* bc  = (const float*)d_in[7];
    const float* Wih = (const float*)d_in[8];
    const float* Whh = (const float*)d_in[9];
    const float* bih = (const float*)d_in[10];
    const float* bhh = (const float*)d_in[11];
    const float* Wo  = (const float*)d_in[12];
    const float* bo  = (const float*)d_in[13];

    float* out = (float*)d_out;   // [V | H | L]
    float* ws  = (float*)d_ws;
    float* elg  = ws;                 // 512
    float* gh   = ws + 512;           // 3072
    float* aa   = ws + 3584;          // 1024 (16B aligned)
    float* xv   = ws + 4608;          // 1024 (16B aligned)
    float* hn   = ws + 5632;          // 1024 (16B aligned)
    float* pm   = ws + 6656;          // 2048
    float* psum = ws + 8704;          // 2048
    float* pbuf = ws + 10752;         // 256*1024 (16B aligned)

    float* out_logits = out;          // V
    float* out_hnew   = out + V;      // H
    float* out_attnw  = out + V + H;  // L

    k_phase1<<<NPART + 768, 256, 0, stream>>>(tok, hid, emb, Wa, ba, enc, Whh, bhh,
                                              elg, pbuf, gh);
    k_reduce<<<16, 256, 0, stream>>>(elg, pbuf, aa, out_attnw);
    k_comb<<<256, 256, 0, stream>>>(tok, emb, aa, Wc, bc, xv);
    k_gates_gru<<<256, 256, 0, stream>>>(xv, hid, Wih, bih, gh, out_hnew, hn);
    k_out_gemv<<<NBGEMV, 256, 0, stream>>>(hn, Wo, bo, out_logits, pm, psum);
    k_finalize<<<197, 256, 0, stream>>>(out_logits, pm, psum);
}

// Round 12
// 55.967 us; speedup vs baseline: 1.0404x; 1.0149x over previous
//
#include <hip/hip_runtime.h>
#include <cmath>

#define H 1024
#define V 50257
#define L 512
#define NBGEMV 1024   // grid-stride GEMV blocks (exactly 4/CU) — R8 best config
#define GSTR (NBGEMV * 4)
#define NPART 256     // attn numerator partials (2 rows each)

typedef float f4 __attribute__((ext_vector_type(4)));

__device__ __forceinline__ float wred_sum(float v) {
#pragma unroll
    for (int o = 32; o > 0; o >>= 1) v += __shfl_xor(v, o, 64);
    return v;
}
__device__ __forceinline__ float dot4f(f4 a, f4 b) {
    return a.x * b.x + a.y * b.y + a.z * b.z + a.w * b.w;
}
__device__ __forceinline__ void ms_merge(float& m, float& s, float m2, float s2) {
    float M = fmaxf(m, m2);
    if (M == -INFINITY) { m = M; s = 0.f; return; }
    s = s * expf(m - M) + s2 * expf(m2 - M);
    m = M;
}

// K1 (1024 blocks, exactly 4/CU, ~uniform 16-24KB per block):
//  blocks [0,256):  2 attn rows; wave wv handles (row = 2b+(wv>>1), k-half = wv&1);
//                   exp-logits -> elg, then 2-row weighted-enc partial -> pbuf[b].
//  blocks [256,1024): gh[j] = h . W_hh[j,:] + b_hh[j], wave-per-row.
__global__ void k_phase1(const int* __restrict__ tok,
                         const float* __restrict__ hid,
                         const float* __restrict__ emb,
                         const float* __restrict__ Wa,
                         const float* __restrict__ ba,
                         const float* __restrict__ enc,
                         const float* __restrict__ Whh,
                         const float* __restrict__ bhh,
                         float* __restrict__ elg,
                         float* __restrict__ pbuf,   // [256][1024]
                         float* __restrict__ gh) {
    const int t = threadIdx.x, lane = t & 63, wv = t >> 6, b = blockIdx.x;
    const f4* h4 = (const f4*)hid;
    if (b < NPART) {
        const int row = 2 * b + (wv >> 1);
        const int half = wv & 1;
        const f4* e4 = (const f4*)(emb + (size_t)tok[0] * H);
        const f4* wr = (const f4*)(Wa + (size_t)row * 2048);
        float acc = 0.f;
#pragma unroll
        for (int k = 0; k < 4; ++k) {
            int f = half * 256 + 64 * k + lane;    // [0, 512)
            f4 s = (f < 256) ? e4[f] : h4[f - 256];
            acc += dot4f(wr[f], s);
        }
        acc = wred_sum(acc);
        __shared__ float sp[4];
        __shared__ float se[2];
        if (lane == 0) sp[wv] = acc;
        __syncthreads();
        if (t == 0) {
            float E0 = expf(sp[0] + sp[1] + ba[2 * b]);
            float E1 = expf(sp[2] + sp[3] + ba[2 * b + 1]);
            se[0] = E0; se[1] = E1;
            elg[2 * b] = E0; elg[2 * b + 1] = E1;
        }
        __syncthreads();
        f4 a = se[0] * ((const f4*)(enc + (size_t)(2 * b) * H))[t]
             + se[1] * ((const f4*)(enc + (size_t)(2 * b + 1) * H))[t];
        ((f4*)pbuf)[b * 256 + t] = a;
    } else {
        const int j = (b - NPART) * 4 + wv;   // [0, 3072)
        const f4* wh = (const f4*)(Whh + (size_t)j * H);
        float acc = 0.f;
#pragma unroll
        for (int k = 0; k < 4; ++k) {
            int f = 64 * k + lane;
            acc += dot4f(wh[f], h4[f]);
        }
        acc = wred_sum(acc);
        if (lane == 0) gh[j] = acc + bhh[j];
    }
}

// K2 (16 blocks): deterministic reduce of 256 partials -> aa (invS-scaled).
//  Block b owns f4-columns [16b, 16b+16); thread (g=t>>4, c=t&15) sums 16 stripes.
//  Block 0 also writes attn_weights.
__global__ void k_reduce(const float* __restrict__ elg,
                         const float* __restrict__ pbuf,
                         float* __restrict__ aa,
                         float* __restrict__ wout) {
    const int t = threadIdx.x, b = blockIdx.x;
    const int g = t >> 4, c = t & 15;
    __shared__ float red[4];
    const float e0 = elg[t], e1 = elg[t + 256];
    float s = wred_sum(e0 + e1);
    if ((t & 63) == 0) red[t >> 6] = s;
    __syncthreads();
    const float invS = 1.f / (red[0] + red[1] + red[2] + red[3]);
    const int col = b * 16 + c;
    f4 a = {0.f, 0.f, 0.f, 0.f};
#pragma unroll
    for (int i = 0; i < 16; ++i)
        a += ((const f4*)pbuf)[(size_t)(g + 16 * i) * 256 + col];
    __shared__ f4 racc[16][16];
    racc[g][c] = a;
    __syncthreads();
    if (g == 0) {
        f4 tot = {0.f, 0.f, 0.f, 0.f};
#pragma unroll
        for (int i = 0; i < 16; ++i) tot += racc[i][c];
        ((f4*)aa)[col] = tot * invS;
    }
    if (b == 0) { wout[t] = e0 * invS; wout[t + 256] = e1 * invS; }
}

// K3 (256 blocks): x[j] = relu([emb, aa] . Wc[j,:] + bc[j]); wave-per-row.
__global__ void k_comb(const int* __restrict__ tok,
                       const float* __restrict__ emb,
                       const float* __restrict__ aa,
                       const float* __restrict__ Wc,
                       const float* __restrict__ bcb,
                       float* __restrict__ xv) {
    const int lane = threadIdx.x & 63, wv = threadIdx.x >> 6;
    const int j = blockIdx.x * 4 + wv;
    const f4* e4 = (const f4*)(emb + (size_t)tok[0] * H);
    const f4* a4 = (const f4*)aa;
    const f4* wr = (const f4*)(Wc + (size_t)j * 2048);
    float acc = 0.f;
#pragma unroll
    for (int k = 0; k < 4; ++k) {
        int f = 64 * k + lane;
        acc += dot4f(wr[f], e4[f]);
        acc += dot4f(wr[256 + f], a4[f]);
    }
    acc = wred_sum(acc);
    if (lane == 0) xv[j] = fmaxf(acc + bcb[j], 0.f);
}

// K4 (256 blocks): fused gates+GRU; wave per j.
__global__ void k_gates_gru(const float* __restrict__ xv,
                            const float* __restrict__ hid,
                            const float* __restrict__ Wih,
                            const float* __restrict__ bih,
                            const float* __restrict__ gh,
                            float* __restrict__ hn_out,
                            float* __restrict__ hn_ws) {
    const int lane = threadIdx.x & 63, wv = threadIdx.x >> 6;
    const int j = blockIdx.x * 4 + wv;
    const f4* x4 = (const f4*)xv;
    f4 xreg[4];
#pragma unroll
    for (int k = 0; k < 4; ++k) xreg[k] = x4[64 * k + lane];
    float g[3];
#pragma unroll
    for (int p = 0; p < 3; ++p) {
        const f4* wr = (const f4*)(Wih + (size_t)(j + p * H) * H);
        float acc = 0.f;
#pragma unroll
        for (int k = 0; k < 4; ++k) acc += dot4f(wr[64 * k + lane], xreg[k]);
        g[p] = wred_sum(acc) + bih[j + p * H];
    }
    if (lane == 0) {
        float r = 1.f / (1.f + expf(-(g[0] + gh[j])));
        float z = 1.f / (1.f + expf(-(g[1] + gh[j + H])));
        float n = tanhf(g[2] + r * gh[j + 2 * H]);
        float hv = (1.f - z) * n + z * hid[j];
        hn_out[j] = hv;
        hn_ws[j] = hv;
    }
}

// K5 (1024 blocks, exactly 4/CU): grid-stride GEMV (R8's proven config —
//  BW-saturated at ~6.1 TB/s; ILP/TLP/nt knobs all measured neutral or worse).
//  Online (m,s) per wave, merged per block.
__global__ void k_out_gemv(const float* __restrict__ hn,
                           const float* __restrict__ Wo,
                           const float* __restrict__ bo,
                           float* __restrict__ logits,
                           float* __restrict__ pm,
                           float* __restrict__ ps) {
    const int lane = threadIdx.x & 63, wv = threadIdx.x >> 6;
    const int b = blockIdx.x;
    const int gw = b * 4 + wv;            // [0, GSTR)
    const f4* h4 = (const f4*)hn;
    f4 hreg[4];
#pragma unroll
    for (int k = 0; k < 4; ++k) hreg[k] = h4[64 * k + lane];
    float m = -INFINITY, s = 0.f;
    for (int v = gw; v < V; v += GSTR) {
        const f4* wr = (const f4*)(Wo + (size_t)v * H);
        float acc = 0.f;
#pragma unroll
        for (int k = 0; k < 4; ++k) acc += dot4f(wr[64 * k + lane], hreg[k]);
        acc = wred_sum(acc) + bo[v];
        if (lane == 0) logits[v] = acc;
        float M = fmaxf(m, acc);
        s = s * expf(m - M) + expf(acc - M);
        m = M;
    }
    __shared__ float smm[4], sms[4];
    if (lane == 0) { smm[wv] = m; sms[wv] = s; }
    __syncthreads();
    if (threadIdx.x == 0) {
        float M = smm[0], S = sms[0];
#pragma unroll
        for (int i = 1; i < 4; ++i) ms_merge(M, S, smm[i], sms[i]);
        pm[b] = M; ps[b] = S;
    }
}

// K6 (197 blocks): redundant (m,s) reduce over 1024 partials -> C; subtract.
__global__ void k_finalize(float* __restrict__ out,
                           const float* __restrict__ pm,
                           const float* __restrict__ ps) {
    const int t = threadIdx.x, lane = t & 63, wv = t >> 6;
    float m = -INFINITY, s = 0.f;
    for (int i = t; i < NBGEMV; i += 256) ms_merge(m, s, pm[i], ps[i]);
#pragma unroll
    for (int o = 32; o > 0; o >>= 1) {
        float m2 = __shfl_xor(m, o, 64);
        float s2 = __shfl_xor(s, o, 64);
        ms_merge(m, s, m2, s2);
    }
    __shared__ float smm[4], sms[4];
    __shared__ float Cs;
    if (lane == 0) { smm[wv] = m; sms[wv] = s; }
    __syncthreads();
    if (t == 0) {
        float M = smm[0], S = sms[0];
#pragma unroll
        for (int i = 1; i < 4; ++i) ms_merge(M, S, smm[i], sms[i]);
        Cs = M + logf(S);
    }
    __syncthreads();
    const float C = Cs;
    const int v = blockIdx.x * 256 + t;
    if (v < V) out[v] -= C;
}

extern "C" void kernel_launch(void* const* d_in, const int* in_sizes, int n_in,
                              void* d_out, int out_size, void* d_ws, size_t ws_size,
                              hipStream_t stream) {
    const int*   tok = (const int*)d_in[0];
    const float* hid = (const float*)d_in[1];
    const float* enc = (const float*)d_in[2];
    const float* emb = (const float*)d_in[3];
    const float* Wa  = (const float*)d_in[4];
    const float* ba  = (const float*)d_in[5];
    const float* Wc  = (const float*)d_in[6];
    const float* bc  = (const float*)d_in[7];
    const float* Wih = (const float*)d_in[8];
    const float* Whh = (const float*)d_in[9];
    const float* bih = (const float*)d_in[10];
    const float* bhh = (const float*)d_in[11];
    const float* Wo  = (const float*)d_in[12];
    const float* bo  = (const float*)d_in[13];

    float* out = (float*)d_out;   // [V | H | L]
    float* ws  = (float*)d_ws;
    float* elg  = ws;                 // 512
    float* gh   = ws + 512;           // 3072
    float* aa   = ws + 3584;          // 1024 (16B aligned)
    float* xv   = ws + 4608;          // 1024 (16B aligned)
    float* hn   = ws + 5632;          // 1024 (16B aligned)
    float* pm   = ws + 6656;          // 1024
    float* psum = ws + 7680;          // 1024
    float* pbuf = ws + 8704;          // 256*1024 (16B aligned)

    float* out_logits = out;          // V
    float* out_hnew   = out + V;      // H
    float* out_attnw  = out + V + H;  // L

    k_phase1<<<NPART + 768, 256, 0, stream>>>(tok, hid, emb, Wa, ba, enc, Whh, bhh,
                                              elg, pbuf, gh);
    k_reduce<<<16, 256, 0, stream>>>(elg, pbuf, aa, out_attnw);
    k_comb<<<256, 256, 0, stream>>>(tok, emb, aa, Wc, bc, xv);
    k_gates_gru<<<256, 256, 0, stream>>>(xv, hid, Wih, bih, gh, out_hnew, hn);
    k_out_gemv<<<NBGEMV, 256, 0, stream>>>(hn, Wo, bo, out_logits, pm, psum);
    k_finalize<<<197, 256, 0, stream>>>(out_logits, pm, psum);
}